// Round 4
// baseline (449.314 us; speedup 1.0000x reference)
//
#include <hip/hip_runtime.h>
#include <hip/hip_bf16.h>

// Problem constants
#define B_   8
#define CIN  64
#define CM   16      // compressed channels
#define H_   192
#define W_   384
#define ND   41      // MAX_DISP+1
#define HW   (H_ * W_)
#define SLOPE 0.1f
#define SMINI ((size_t)B_ * CM * H_ * W_)   // elems per compressed tensor

typedef __attribute__((ext_vector_type(8))) short short8v;   // 8 bf16 = 1 MFMA frag
typedef __attribute__((ext_vector_type(4))) float floatx4;

__device__ __forceinline__ float bf2f(short h) {
    union { unsigned u; float f; } cv;
    cv.u = ((unsigned)(unsigned short)h) << 16;
    return cv.f;
}
__device__ __forceinline__ short f2bf(float f) {
    __hip_bfloat16 h = __float2bfloat16(f);   // RNE
    return *(short*)&h;
}

// async global->LDS DMA, 16 B per lane. LDS dest = wave-uniform base + lane*16;
// global src is PER-LANE (m173) -> swizzled layouts via pre-swizzled source.
__device__ __forceinline__ void gload_lds16(const void* g, void* l) {
    __builtin_amdgcn_global_load_lds(
        (const __attribute__((address_space(1))) void*)g,
        (__attribute__((address_space(3))) void*)l, 16, 0, 0);
}

// ---------------------------------------------------------------------------
// Kernel 0: reorder weights OIHW fp32 -> [co][k] bf16 with k = (dy*3+dx)*64 + c
// ---------------------------------------------------------------------------
__global__ void wprep_kernel(const float* __restrict__ w, short* __restrict__ wbf) {
    int i = blockIdx.x * 256 + threadIdx.x;
    if (i >= CM * 576) return;
    int co = i / 576, k = i - co * 576;
    int t = k >> 6, c = k & 63;               // k = t*64 + c
    wbf[i] = f2bf(w[(co * CIN + c) * 9 + t]); // w[co][c][dy][dx], t = dy*3+dx
}

// ---------------------------------------------------------------------------
// Kernel T: NCHW fp32 -> NHWC bf16 transpose prepass.
// Per block: (t,b,y,xhalf): 64 c x 192 x tile. Read 768-B runs per channel,
// write fully dense (8 px * 128 B = 1 KB contiguous per 64 lanes).
// ---------------------------------------------------------------------------
#define TXW  192
#define TSTR 72    // shorts per pixel row in LDS ([x][c], pad 64->72)

__global__ __launch_bounds__(256) void txp_kernel(
    const float* __restrict__ ina, const float* __restrict__ inb,
    short* __restrict__ xT)
{
    __shared__ __align__(16) short xl[TXW * TSTR];   // 27,648 B
    int blk = blockIdx.x;
    blk = (blk & 7) * (gridDim.x >> 3) + (blk >> 3);   // XCD swizzle (6144%8==0)
    int xh = blk & 1;  blk >>= 1;
    int y  = blk % H_; blk /= H_;
    int b  = blk & 7;
    int t  = blk >> 3;
    const float* src = t ? inb : ina;
    int tid = threadIdx.x;

    // stage-in: 64 c x 48 float4 (=192 x) = 3072 items, 12/thread
    #pragma unroll
    for (int i = 0; i < 12; ++i) {
        int e = i * 256 + tid;          // 0..3071
        int xq = e % 48;
        int c  = e / 48;                // 0..63
        floatx4 v = *(const floatx4*)(src + (size_t)(b * CIN + c) * HW
                                      + (size_t)y * W_ + xh * TXW + xq * 4);
        int x4 = xq * 4;
        xl[(x4 + 0) * TSTR + c] = f2bf(v[0]);
        xl[(x4 + 1) * TSTR + c] = f2bf(v[1]);
        xl[(x4 + 2) * TSTR + c] = f2bf(v[2]);
        xl[(x4 + 3) * TSTR + c] = f2bf(v[3]);
    }
    __syncthreads();

    // stage-out: 192 px x 8 cgroups = 1536 items of 16 B, 6/thread
    size_t obase = (((size_t)(t * B_ + b) * H_ + y) * W_ + xh * TXW) * 64;
    #pragma unroll
    for (int i = 0; i < 6; ++i) {
        int e = i * 256 + tid;          // 0..1535
        int cg = e & 7, x = e >> 3;
        short8v q = *(const short8v*)(xl + x * TSTR + cg * 8);
        *(short8v*)(xT + obase + (size_t)x * 64 + cg * 8) = q;
    }
}

// ---------------------------------------------------------------------------
// Kernel 1 (new): 3x3 conv 64->16 + bias + LeakyReLU, MFMA implicit GEMM,
// staging NHWC bf16 via global_load_lds (16 B/lane, 34 DMA instrs per block,
// 34,816 B LDS). LDS [site][64c] linear, site stride 128 B; 2-bit XOR swizzle
// ((site&3)<<4 on byte addr) applied on SOURCE and on READ (T21 both-sides).
// Boundary blocks pre-zero LDS and predicate the DMA (masked lanes skip).
// ---------------------------------------------------------------------------
__global__ __launch_bounds__(256, 4) void conv_dma(
    const short* __restrict__ xT, const short* __restrict__ wbf,
    const float* __restrict__ bias, short* __restrict__ mini)
{
    __shared__ __align__(16) short px[272 * 64];   // 34,816 B
    int blk = blockIdx.x;
    blk = (blk & 7) * (gridDim.x >> 3) + (blk >> 3);   // XCD swizzle
    int xt = blk % 12;  blk /= 12;
    int yt = blk % 32;  blk /= 32;
    int b  = blk & 7;
    int t  = blk >> 3;
    int x0 = xt * 32, y0 = yt * 6;
    int tid  = threadIdx.x;
    int lane = tid & 63, wv = tid >> 6;

    const char* xTb = (const char*)xT;
    char* pxb = (char*)px;
    size_t pbase = (size_t)(t * B_ + b) * H_ * W_;   // pixel index base

    bool edge = (yt == 0) | (yt == 31) | (xt == 0) | (xt == 11);
    if (edge) {     // block-uniform branch
        #pragma unroll
        for (int i = 0; i < 17; ++i)
            *(unsigned long long*)(pxb + (i * 256 + tid) * 8) = 0ull;
        __syncthreads();
    }

    // ---- issue DMA: 34 instrs, waves get {8,8,8,8} + waves 0,1 one extra ----
    int sub = lane >> 3;            // site within 8-site group
    int opc = (lane & 7) << 4;      // linear 16-B chunk within pixel
    auto issue = [&](int k) {
        int s   = k * 8 + sub;              // 0..271
        int row = (s * 241) >> 13;          // s / 34 (valid for s < 272)
        int lx  = s - row * 34;
        int gy  = y0 - 1 + row, gx = x0 - 1 + lx;
        int o   = opc ^ ((s & 3) << 4);     // inverse swizzle on source
        const char* gp = xTb + ((pbase + (size_t)gy * W_ + gx) * 128 + o);
        void* lp = pxb + k * 1024;
        if (!edge) {
            gload_lds16(gp, lp);
        } else if (((unsigned)gy < (unsigned)H_) & ((unsigned)gx < (unsigned)W_)) {
            gload_lds16(gp, lp);
        }
    };
    #pragma unroll
    for (int i = 0; i < 8; ++i) issue(wv * 8 + i);
    if (wv < 2) issue(32 + wv);

    // ---- weight A-frags (overlap with DMA flight) ----
    int n16 = lane & 15, quad = lane >> 4;
    short8v af[18];
    #pragma unroll
    for (int ks = 0; ks < 18; ++ks)
        af[ks] = *(const short8v*)(wbf + n16 * 576 + ks * 32 + quad * 8);

    __syncthreads();   // drains vmcnt(0) (DMA + af) before any LDS read

    // ---- MFMA main loop: 3 M-tiles per wave, 18 K-steps ----
    floatx4 acc[3] = {{0,0,0,0},{0,0,0,0},{0,0,0,0}};
    int base128[3];
    int Zj[3][4];      // read-side swizzle: (quad*16) ^ (((2*r_j+n16+m)&3)<<4)
    #pragma unroll
    for (int j = 0; j < 3; ++j) {
        int mt = wv * 3 + j;
        int r = mt >> 1, xb = (mt & 1) << 4;
        base128[j] = (r * 34 + xb + n16) * 128;
        #pragma unroll
        for (int m = 0; m < 4; ++m)
            Zj[j][m] = (quad << 4) ^ (((2 * r + n16 + m) & 3) << 4);
    }
    #pragma unroll
    for (int ks = 0; ks < 18; ++ks) {
        const int tap = ks >> 1, ch = ks & 1;
        const int dy = tap / 3, dx = tap % 3;
        const int d = dy * 34 + dx;                    // site delta
        #pragma unroll
        for (int j = 0; j < 3; ++j) {
            short8v bfr = *(const short8v*)(pxb + base128[j] + Zj[j][d & 3]
                                            + (d * 128 + ch * 64));
            acc[j] = __builtin_amdgcn_mfma_f32_16x16x32_bf16(af[ks], bfr, acc[j], 0, 0, 0);
        }
    }

    // ---- epilogue: bias + LeakyReLU, bf16 NHWC store ----
    float bia[4];
    #pragma unroll
    for (int i = 0; i < 4; ++i) bia[i] = bias[quad * 4 + i];
    #pragma unroll
    for (int j = 0; j < 3; ++j) {
        int mt = wv * 3 + j;
        int r = mt >> 1, xb = (mt & 1) << 4;
        int y = y0 + r, x = x0 + xb + n16;
        size_t o = (((size_t)(t * B_ + b) * H_ + y) * W_ + x) * CM + quad * 4;
        short4 q;
        float v2;
        v2 = acc[j][0] + bia[0]; v2 = v2 >= 0.f ? v2 : SLOPE * v2; q.x = f2bf(v2);
        v2 = acc[j][1] + bia[1]; v2 = v2 >= 0.f ? v2 : SLOPE * v2; q.y = f2bf(v2);
        v2 = acc[j][2] + bia[2]; v2 = v2 >= 0.f ? v2 : SLOPE * v2; q.z = f2bf(v2);
        v2 = acc[j][3] + bia[3]; v2 = v2 >= 0.f ? v2 : SLOPE * v2; q.w = f2bf(v2);
        *(short4*)(mini + o) = q;
    }
}

// ---------------------------------------------------------------------------
// Legacy conv (r2 variant): fallback if workspace too small for xT.
// ---------------------------------------------------------------------------
#define LC 34
#define PSTR 72

__global__ __launch_bounds__(256, 4) void conv_mfma(
    const float* __restrict__ ina, const float* __restrict__ inb,
    const short* __restrict__ wbf, const float* __restrict__ bias,
    short* __restrict__ mini)
{
    __shared__ __align__(16) short pxl[8 * LC * PSTR];
    int blk = blockIdx.x;
    int xt = blk % 12;  blk /= 12;
    int yt = blk % 32;  blk /= 32;
    int b  = blk & 7;
    int t  = blk >> 3;
    const float* src = t ? inb : ina;
    int x0 = xt * 32, y0 = yt * 6;
    int tid = threadIdx.x;

    int t4 = tid >> 4;
    int cq = tid & 15;
    int c0 = cq << 2;
    floatx4 v[5][4];
    int wbase_[5], lxb_[5];
    bool vld[5];
    #pragma unroll
    for (int i = 0; i < 5; ++i) {
        int g = i * 16 + t4;
        int xq = g % 10;
        int row = g / 10;
        int gy = y0 - 1 + row;
        int gx = x0 - 4 + xq * 4;
        bool ok = ((unsigned)gy < (unsigned)H_) && ((unsigned)gx < (unsigned)W_);
        vld[i] = ok;
        int lxb = gx - x0 + 1;
        lxb_[i] = lxb;
        wbase_[i] = (row * LC + lxb) * PSTR + c0;
        int gyc = ok ? gy : 0;
        int gxc = ok ? gx : 0;
        const float* p = src + (size_t)(b * CIN + c0) * HW + (size_t)gyc * W_ + gxc;
        v[i][0] = *(const floatx4*)p;
        v[i][1] = *(const floatx4*)(p + HW);
        v[i][2] = *(const floatx4*)(p + 2 * HW);
        v[i][3] = *(const floatx4*)(p + 3 * HW);
    }
    #pragma unroll
    for (int i = 0; i < 5; ++i) {
        #pragma unroll
        for (int j = 0; j < 4; ++j) {
            if ((unsigned)(lxb_[i] + j) < (unsigned)LC) {
                float f0 = vld[i] ? v[i][0][j] : 0.f;
                float f1 = vld[i] ? v[i][1][j] : 0.f;
                float f2 = vld[i] ? v[i][2][j] : 0.f;
                float f3 = vld[i] ? v[i][3][j] : 0.f;
                short4 q;
                q.x = f2bf(f0); q.y = f2bf(f1);
                q.z = f2bf(f2); q.w = f2bf(f3);
                *(short4*)(pxl + wbase_[i] + j * PSTR) = q;
            }
        }
    }
    int lane = tid & 63;
    int n16  = lane & 15;
    int quad = lane >> 4;
    short8v af[18];
    #pragma unroll
    for (int ks = 0; ks < 18; ++ks)
        af[ks] = *(const short8v*)(wbf + n16 * 576 + ks * 32 + quad * 8);
    __syncthreads();
    int wv = tid >> 6;
    floatx4 acc[3] = {{0,0,0,0},{0,0,0,0},{0,0,0,0}};
    int base[3];
    #pragma unroll
    for (int j = 0; j < 3; ++j) {
        int mt = wv * 3 + j;
        int r = mt >> 1, xb = (mt & 1) << 4;
        base[j] = (r * LC + xb + n16) * PSTR + quad * 8;
    }
    #pragma unroll
    for (int ks = 0; ks < 18; ++ks) {
        const int tap = ks >> 1, ch = ks & 1;
        const int dy = tap / 3, dx = tap % 3;
        const int off = (dy * LC + dx) * PSTR + ch * 32;
        #pragma unroll
        for (int j = 0; j < 3; ++j) {
            short8v bfr = *(const short8v*)(pxl + base[j] + off);
            acc[j] = __builtin_amdgcn_mfma_f32_16x16x32_bf16(af[ks], bfr, acc[j], 0, 0, 0);
        }
    }
    float bia[4];
    #pragma unroll
    for (int i = 0; i < 4; ++i) bia[i] = bias[quad * 4 + i];
    #pragma unroll
    for (int j = 0; j < 3; ++j) {
        int mt = wv * 3 + j;
        int r = mt >> 1, xb = (mt & 1) << 4;
        int y = y0 + r, x = x0 + xb + n16;
        size_t o = (((size_t)(t * B_ + b) * H_ + y) * W_ + x) * CM + quad * 4;
        short4 q;
        float v2;
        v2 = acc[j][0] + bia[0]; v2 = v2 >= 0.f ? v2 : SLOPE * v2; q.x = f2bf(v2);
        v2 = acc[j][1] + bia[1]; v2 = v2 >= 0.f ? v2 : SLOPE * v2; q.y = f2bf(v2);
        v2 = acc[j][2] + bia[2]; v2 = v2 >= 0.f ? v2 : SLOPE * v2; q.z = f2bf(v2);
        v2 = acc[j][3] + bia[3]; v2 = v2 >= 0.f ? v2 : SLOPE * v2; q.w = f2bf(v2);
        *(short4*)(mini + o) = q;
    }
}

// ---------------------------------------------------------------------------
// Kernel 2: 41-disparity correlation over NHWC bf16 mini (unchanged).
// ---------------------------------------------------------------------------
#define BSTR 24

__global__ __launch_bounds__(384) void corr_nhwc(
    const short* __restrict__ mini, float* __restrict__ out)
{
    __shared__ __align__(16) short bl[W_ * BSTR];
    int b = blockIdx.x / H_;
    int y = blockIdx.x % H_;
    int x = threadIdx.x;

    size_t arow = ((size_t)b * H_ + y) * W_ * CM;
    size_t brow = ((size_t)(B_ + b) * H_ + y) * W_ * CM;

    short8v p0 = *(const short8v*)(mini + brow + (size_t)x * CM);
    short8v p1 = *(const short8v*)(mini + brow + (size_t)x * CM + 8);
    *(short8v*)(bl + x * BSTR) = p0;
    *(short8v*)(bl + x * BSTR + 8) = p1;

    float av[16];
    short8v a0 = *(const short8v*)(mini + arow + (size_t)x * CM);
    short8v a1 = *(const short8v*)(mini + arow + (size_t)x * CM + 8);
    #pragma unroll
    for (int i = 0; i < 8; ++i) { av[i] = bf2f(a0[i]); av[8 + i] = bf2f(a1[i]); }

    __syncthreads();

    float* ob = out + ((size_t)b * ND * H_ + y) * W_ + x;
    #pragma unroll 1
    for (int d = 0; d < ND; ++d) {
        float s = 0.f;
        int xs = x - d;
        if (xs >= 0) {
            const short* bp = bl + xs * BSTR;
            short8v c0 = *(const short8v*)bp;
            short8v c1 = *(const short8v*)(bp + 8);
            float s0 = 0.f, s1 = 0.f;
            #pragma unroll
            for (int i = 0; i < 8; ++i) {
                s0 += av[i]     * bf2f(c0[i]);
                s1 += av[8 + i] * bf2f(c1[i]);
            }
            s = s0 + s1;
        }
        ob[(size_t)d * HW] = s * 0.0625f;
    }
}

// ---------------------------------------------------------------------------
extern "C" void kernel_launch(void* const* d_in, const int* in_sizes, int n_in,
                              void* d_out, int out_size, void* d_ws, size_t ws_size,
                              hipStream_t stream) {
    const float* conv1a = (const float*)d_in[0];
    const float* conv1b = (const float*)d_in[1];
    const float* W_comp = (const float*)d_in[2];
    const float* b_comp = (const float*)d_in[3];
    float* out = (float*)d_out;

    short* mini = (short*)d_ws;                 // 37,748,736 B
    short* wbf  = mini + 2 * SMINI;             // 18,432 B (128-B aligned end)
    short* xT   = wbf + 9216;                   // NHWC bf16, 150,994,944 B
    const size_t need = 37748736ull + 18432ull + 150994944ull;

    wprep_kernel<<<36, 256, 0, stream>>>(W_comp, wbf);
    if (ws_size >= need) {
        txp_kernel<<<6144, 256, 0, stream>>>(conv1a, conv1b, xT);
        conv_dma<<<6144, 256, 0, stream>>>(xT, wbf, b_comp, mini);
    } else {
        conv_mfma<<<6144, 256, 0, stream>>>(conv1a, conv1b, wbf, b_comp, mini);
    }
    corr_nhwc<<<B_ * H_, 384, 0, stream>>>(mini, out);
}